// Round 1
// baseline (240.232 us; speedup 1.0000x reference)
//
#include <hip/hip_runtime.h>
#include <hip/hip_bf16.h>

// Problem constants (fixed by reference): B=8, C=128, N=M=4096, OUT=128
#define BATCH 8
#define CDIM 128
#define NDIM 4096

typedef __bf16 bf16x8 __attribute__((ext_vector_type(8)));
typedef float f32x4 __attribute__((ext_vector_type(4)));

// workspace layout (bytes)
#define QT_OFF 0u                      // bf16 [8][4096][128]  normalized target_g, transposed
#define KT_OFF 8388608u                // bf16 [8][4096][128]  normalized input, transposed
#define VB_OFF 16777216u               // bf16 [8][128][4096]  raw input
#define WT_OFF 25165824u               // bf16 [128][128]      weight transposed: wT[o][c]
#define SC_OFF (WT_OFF + 32768u)       // f32 [128] scale = gamma*rsqrt(var+eps)
#define BI_OFF (SC_OFF + 512u)         // f32 [128] bias  = beta - mean*scale

__device__ __forceinline__ f32x4 mfma16(bf16x8 a, bf16x8 b, f32x4 c) {
    return __builtin_amdgcn_mfma_f32_16x16x32_bf16(a, b, c, 0, 0, 0);
}

// ---------------------------------------------------------------------------
// Pass 1a: per-column L2 normalize over C + transpose to [n][c] bf16.
// z==0: input -> Kt (normalized, transposed) + Vb (raw bf16, natural layout)
// z==1: target_g -> Qt (normalized, transposed)
// ---------------------------------------------------------------------------
__global__ __launch_bounds__(256) void prep_nt(const float* __restrict__ input,
                                               const float* __restrict__ tg,
                                               void* __restrict__ ws) {
    __shared__ float T[128][65];   // padded: bank-conflict-free column reads
    __shared__ float rn[64];
    const int n0 = blockIdx.x * 64;
    const int b  = blockIdx.y;
    const int tid = threadIdx.x;
    const float* src = (blockIdx.z == 0 ? input : tg) + (size_t)b * CDIM * NDIM;

    // load 128 x 64 tile (float4 along n, coalesced)
    #pragma unroll
    for (int i = 0; i < 8; ++i) {
        int f = tid + i * 256;          // 0..2047 float4 slots
        int c = f >> 4;
        int j4 = f & 15;
        float4 v = *(const float4*)(src + (size_t)c * NDIM + n0 + j4 * 4);
        T[c][j4 * 4 + 0] = v.x;
        T[c][j4 * 4 + 1] = v.y;
        T[c][j4 * 4 + 2] = v.z;
        T[c][j4 * 4 + 3] = v.w;
    }
    __syncthreads();
    if (tid < 64) {
        float ss = 0.f;
        #pragma unroll 8
        for (int c = 0; c < 128; ++c) { float x = T[c][tid]; ss += x * x; }
        rn[tid] = 1.0f / fmaxf(sqrtf(ss), 1e-12f);
    }
    __syncthreads();

    if (blockIdx.z == 0) {
        __hip_bfloat16* kt = (__hip_bfloat16*)((char*)ws + KT_OFF) + ((size_t)b * NDIM + n0) * CDIM;
        #pragma unroll
        for (int i = 0; i < 32; ++i) {
            int f = tid + i * 256;      // 8192 elements
            int j = f >> 7, c = f & 127;
            kt[j * CDIM + c] = __hip_bfloat16(T[c][j] * rn[j]);
        }
        __hip_bfloat16* vb = (__hip_bfloat16*)((char*)ws + VB_OFF) + (size_t)b * CDIM * NDIM + n0;
        #pragma unroll
        for (int i = 0; i < 32; ++i) {
            int f = tid + i * 256;
            int c = f >> 6, j = f & 63;
            vb[(size_t)c * NDIM + j] = __hip_bfloat16(T[c][j]);
        }
    } else {
        __hip_bfloat16* qt = (__hip_bfloat16*)((char*)ws + QT_OFF) + ((size_t)b * NDIM + n0) * CDIM;
        #pragma unroll
        for (int i = 0; i < 32; ++i) {
            int f = tid + i * 256;
            int j = f >> 7, c = f & 127;
            qt[j * CDIM + c] = __hip_bfloat16(T[c][j] * rn[j]);
        }
    }
}

// ---------------------------------------------------------------------------
// Pass 1b: transpose weight to bf16 wT[o][c]; fold BN into scale/bias.
// ---------------------------------------------------------------------------
__global__ __launch_bounds__(256) void prep_w(const float* __restrict__ wgt,
                                              const float* __restrict__ gamma,
                                              const float* __restrict__ beta,
                                              const float* __restrict__ mean,
                                              const float* __restrict__ var,
                                              void* __restrict__ ws) {
    __hip_bfloat16* wT = (__hip_bfloat16*)((char*)ws + WT_OFF);
    float* sc = (float*)((char*)ws + SC_OFF);
    float* bi = (float*)((char*)ws + BI_OFF);
    const int tid = threadIdx.x;
    #pragma unroll
    for (int i = 0; i < 64; ++i) {
        int f = tid + i * 256;          // 16384
        int c = f >> 7, o = f & 127;
        wT[o * 128 + c] = __hip_bfloat16(wgt[c * 128 + o]);
    }
    if (tid < 128) {
        float inv = rsqrtf(var[tid] + 1e-5f);
        float s = inv * gamma[tid];
        sc[tid] = s;
        bi[tid] = beta[tid] - mean[tid] * s;
    }
}

// ---------------------------------------------------------------------------
// Pass 2: flash attention + projection + LeakyReLU + BN + transposed store.
// Grid (64 m-tiles, 8 batches), 256 threads = 4 waves, each wave owns 16 rows.
// Static softmax max (cos-sim logits <= ~1): P = exp(S - 1); l via ones-MFMA.
// ---------------------------------------------------------------------------
__global__ __launch_bounds__(256, 2) void flash_kernel(const void* __restrict__ ws_,
                                                       float* __restrict__ out) {
    const char* ws = (const char*)ws_;
    const __hip_bfloat16* Qt = (const __hip_bfloat16*)(ws + QT_OFF);
    const __hip_bfloat16* Kt = (const __hip_bfloat16*)(ws + KT_OFF);
    const __hip_bfloat16* Vb = (const __hip_bfloat16*)(ws + VB_OFF);
    const __hip_bfloat16* wT = (const __hip_bfloat16*)(ws + WT_OFF);
    const float* scale = (const float*)(ws + SC_OFF);
    const float* bias  = (const float*)(ws + BI_OFF);

    // LDS carve: sV [128][72] bf16 @0 (18432B), sK [64][136] bf16 @18432 (17408B),
    // sP per-wave [16][64] bf16 swizzled @35840+w*2048 (8192B total).
    // Epilogue reuse: sAgg [64][136] bf16 @0, sRes [128][68] f32 @18432 (34816B).
    __shared__ alignas(16) char smem[53248];
    __hip_bfloat16* sV = (__hip_bfloat16*)smem;
    __hip_bfloat16* sK = (__hip_bfloat16*)(smem + 18432);

    const int b  = blockIdx.y;
    const int m0 = blockIdx.x * 64;
    const int tid = threadIdx.x;
    const int w = tid >> 6, lane = tid & 63;
    const int li = lane & 15, q = lane >> 4;
    __hip_bfloat16* sP = (__hip_bfloat16*)(smem + 35840 + w * 2048);

    // Q A-fragments resident in registers: A[m=li][k=ks*32+q*8+j]
    bf16x8 qf[4];
    {
        const __hip_bfloat16* qrow = Qt + ((size_t)(b * NDIM + m0 + w * 16 + li)) * CDIM;
        #pragma unroll
        for (int ks = 0; ks < 4; ++ks)
            qf[ks] = *(const bf16x8*)(qrow + ks * 32 + q * 8);
    }

    const f32x4 z4 = {0.f, 0.f, 0.f, 0.f};
    f32x4 oacc[8];
    #pragma unroll
    for (int cb = 0; cb < 8; ++cb) oacc[cb] = z4;
    f32x4 lacc = z4;

    // constant ones B-fragment: B[k][col] = (col==0) ? 1 : 0
    bf16x8 onesf;
    {
        __bf16 ov = (li == 0) ? (__bf16)1.0f : (__bf16)0.0f;
        #pragma unroll
        for (int j = 0; j < 8; ++j) onesf[j] = ov;
    }

    const __hip_bfloat16* kgb = Kt + (size_t)b * NDIM * CDIM;
    const __hip_bfloat16* vgb = Vb + (size_t)b * CDIM * NDIM;

    for (int n0 = 0; n0 < NDIM; n0 += 64) {
        __syncthreads();   // previous tile fully consumed
        {   // stage K tile: 64 rows x 128 c, source is 16KB contiguous
            const __hip_bfloat16* kg = kgb + (size_t)n0 * CDIM;
            #pragma unroll
            for (int i = 0; i < 4; ++i) {
                int f = tid + i * 256;
                int n = f >> 4, cc = f & 15;
                *(bf16x8*)(sK + n * 136 + cc * 8) = *(const bf16x8*)(kg + f * 8);
            }
            // stage V tile: 128 rows x 64 n (natural layout)
            const __hip_bfloat16* vg = vgb + n0;
            #pragma unroll
            for (int i = 0; i < 4; ++i) {
                int f = tid + i * 256;
                int c = f >> 3, j = f & 7;
                *(bf16x8*)(sV + c * 72 + j * 8) = *(const bf16x8*)(vg + (size_t)c * NDIM + j * 8);
            }
        }
        __syncthreads();

        // S = Q · K^T  (B-frag: B[k=c][n-col=li] = K[n][c], c contiguous in sK)
        f32x4 sacc[4];
        #pragma unroll
        for (int nb = 0; nb < 4; ++nb) sacc[nb] = z4;
        #pragma unroll
        for (int ks = 0; ks < 4; ++ks) {
            #pragma unroll
            for (int nb = 0; nb < 4; ++nb) {
                bf16x8 kf = *(const bf16x8*)(sK + (nb * 16 + li) * 136 + ks * 32 + q * 8);
                sacc[nb] = mfma16(qf[ks], kf, sacc[nb]);
            }
        }

        // P = exp(S - 1): C-layout (row=q*4+r, col=nb*16+li) -> swizzled LDS
        #pragma unroll
        for (int nb = 0; nb < 4; ++nb) {
            #pragma unroll
            for (int r = 0; r < 4; ++r) {
                float p = __expf(sacc[nb][r] - 1.0f);
                int row = q * 4 + r;
                int nl  = nb * 16 + li;
                int ch  = (nl >> 3) ^ (row & 7);
                sP[row * 64 + ch * 8 + (nl & 7)] = __hip_bfloat16(p);
            }
        }

        // O += P·V ;  l += P·1  (per-wave private sP, no barrier needed)
        #pragma unroll
        for (int ks2 = 0; ks2 < 2; ++ks2) {
            int pch = (ks2 * 4 + q) ^ (li & 7);
            bf16x8 pf = *(const bf16x8*)(sP + li * 64 + pch * 8);
            lacc = mfma16(pf, onesf, lacc);
            #pragma unroll
            for (int cb = 0; cb < 8; ++cb) {
                bf16x8 vf = *(const bf16x8*)(sV + (cb * 16 + li) * 72 + ks2 * 32 + q * 8);
                oacc[cb] = mfma16(pf, vf, oacc[cb]);
            }
        }
    }

    // l lives in col 0 of each quad -> broadcast, reciprocal
    float linv[4];
    #pragma unroll
    for (int r = 0; r < 4; ++r) {
        float lv = __shfl(lacc[r], lane & 48, 64);
        linv[r] = 1.0f / lv;
    }

    __syncthreads();   // all waves done with sV/sK before reuse
    __hip_bfloat16* sAgg = (__hip_bfloat16*)smem;   // [64][136]
    #pragma unroll
    for (int cb = 0; cb < 8; ++cb) {
        #pragma unroll
        for (int r = 0; r < 4; ++r)
            sAgg[(w * 16 + q * 4 + r) * 136 + cb * 16 + li] =
                __hip_bfloat16(oacc[cb][r] * linv[r]);
    }

    // projection: res[m][o] = sum_c agg[m][c] * wT[o][c]
    f32x4 racc[8];
    #pragma unroll
    for (int ob = 0; ob < 8; ++ob) racc[ob] = z4;
    #pragma unroll
    for (int ks = 0; ks < 4; ++ks) {
        bf16x8 af = *(const bf16x8*)(sAgg + (w * 16 + li) * 136 + ks * 32 + q * 8);
        #pragma unroll
        for (int ob = 0; ob < 8; ++ob) {
            bf16x8 wf = *(const bf16x8*)(wT + (ob * 16 + li) * CDIM + ks * 32 + q * 8);
            racc[ob] = mfma16(af, wf, racc[ob]);
        }
    }

    // LeakyReLU + BN(eval) -> transpose buffer
    float* sRes = (float*)(smem + 18432);           // [128][68]
    #pragma unroll
    for (int ob = 0; ob < 8; ++ob) {
        int o = ob * 16 + li;
        float sc = scale[o], bi = bias[o];
        #pragma unroll
        for (int r = 0; r < 4; ++r) {
            float v = racc[ob][r];
            v = (v >= 0.0f) ? v : 0.01f * v;
            v = v * sc + bi;
            sRes[o * 68 + (w * 16 + q * 4 + r)] = v;
        }
    }
    __syncthreads();

    // coalesced store: out[b][o][m0..m0+63]
    float* outb = out + (size_t)b * CDIM * NDIM + m0;
    #pragma unroll
    for (int i = 0; i < 8; ++i) {
        int f = tid + i * 256;          // 2048 float4s
        int o = f >> 4, mq = f & 15;
        float4 v = *(const float4*)(sRes + o * 68 + mq * 4);
        *(float4*)(outb + (size_t)o * NDIM + mq * 4) = v;
    }
}

extern "C" void kernel_launch(void* const* d_in, const int* in_sizes, int n_in,
                              void* d_out, int out_size, void* d_ws, size_t ws_size,
                              hipStream_t stream) {
    const float* input  = (const float*)d_in[0];
    const float* tg     = (const float*)d_in[1];
    const float* weight = (const float*)d_in[2];
    const float* gamma  = (const float*)d_in[3];
    const float* beta   = (const float*)d_in[4];
    const float* rmean  = (const float*)d_in[5];
    const float* rvar   = (const float*)d_in[6];
    float* out = (float*)d_out;

    (void)in_sizes; (void)n_in; (void)out_size; (void)ws_size;

    dim3 gprep(NDIM / 64, BATCH, 2);
    prep_nt<<<gprep, 256, 0, stream>>>(input, tg, d_ws);
    prep_w<<<dim3(1), 256, 0, stream>>>(weight, gamma, beta, rmean, rvar, d_ws);
    dim3 gflash(NDIM / 64, BATCH);
    flash_kernel<<<gflash, 256, 0, stream>>>(d_ws, out);
}

// Round 2
// 201.696 us; speedup vs baseline: 1.1911x; 1.1911x over previous
//
#include <hip/hip_runtime.h>
#include <hip/hip_bf16.h>

// Problem constants (fixed by reference): B=8, C=128, N=M=4096, OUT=128
#define BATCH 8
#define CDIM 128
#define NDIM 4096

typedef __bf16 bf16x8 __attribute__((ext_vector_type(8)));
typedef float f32x4 __attribute__((ext_vector_type(4)));

// workspace layout (bytes)
#define QT_OFF 0u                      // bf16 [8][4096][128]  normalized target_g, transposed
#define KT_OFF 8388608u                // bf16 [8][4096][128]  normalized input, transposed
#define VB_OFF 16777216u               // bf16 [8][128][4096]  raw input
#define WT_OFF 25165824u               // bf16 [128][128]      weight transposed: wT[o][c]
#define SC_OFF (WT_OFF + 32768u)       // f32 [128] scale = gamma*rsqrt(var+eps)
#define BI_OFF (SC_OFF + 512u)         // f32 [128] bias  = beta - mean*scale

__device__ __forceinline__ f32x4 mfma16(bf16x8 a, bf16x8 b, f32x4 c) {
    return __builtin_amdgcn_mfma_f32_16x16x32_bf16(a, b, c, 0, 0, 0);
}

__device__ __forceinline__ unsigned pack2bf(float a, float b) {
    unsigned short ul = __builtin_bit_cast(unsigned short, (__bf16)a);
    unsigned short uh = __builtin_bit_cast(unsigned short, (__bf16)b);
    return (unsigned)ul | ((unsigned)uh << 16);
}

// async global->LDS, 16B per lane; LDS dest is wave-uniform base + lane*16
__device__ __forceinline__ void glds16(const void* g, void* l) {
    __builtin_amdgcn_global_load_lds((__attribute__((address_space(1))) void*)(void*)g,
                                     (__attribute__((address_space(3))) void*)l, 16, 0, 0);
}

// ---------------------------------------------------------------------------
// Pass 1a: per-column L2 normalize over C + transpose to [n][c] bf16.
// z==0: input -> Kt (normalized, transposed) + Vb (raw bf16, natural layout)
// z==1: target_g -> Qt (normalized, transposed)
// All 256 threads participate in the sum-square reduction; packed stores.
// ---------------------------------------------------------------------------
__global__ __launch_bounds__(256) void prep_nt(const float* __restrict__ input,
                                               const float* __restrict__ tg,
                                               void* __restrict__ ws) {
    __shared__ float T[128][68];   // pitch 68: float4-aligned rows, 4-bank step
    __shared__ float psum[4][64];
    __shared__ float rn[64];
    const int n0 = blockIdx.x * 64;
    const int b  = blockIdx.y;
    const int tid = threadIdx.x;
    const float* src = (blockIdx.z == 0 ? input : tg) + (size_t)b * CDIM * NDIM;

    // load 128 x 64 tile (float4 along n, coalesced)
    #pragma unroll
    for (int i = 0; i < 8; ++i) {
        int f = tid + i * 256;          // 0..2047 float4 slots
        int c = f >> 4;
        int j4 = f & 15;
        *(float4*)&T[c][j4 * 4] = *(const float4*)(src + (size_t)c * NDIM + n0 + j4 * 4);
    }
    __syncthreads();
    {   // parallel sum-square: 4 partials per column
        int j = tid & 63, part = tid >> 6;
        float ss = 0.f;
        #pragma unroll 8
        for (int c = part * 32; c < part * 32 + 32; ++c) { float x = T[c][j]; ss += x * x; }
        psum[part][j] = ss;
    }
    __syncthreads();
    if (tid < 64) {
        float s = psum[0][tid] + psum[1][tid] + psum[2][tid] + psum[3][tid];
        rn[tid] = 1.0f / fmaxf(sqrtf(s), 1e-12f);
    }
    __syncthreads();

    if (blockIdx.z == 0) {
        __hip_bfloat16* kt = (__hip_bfloat16*)((char*)ws + KT_OFF) + ((size_t)b * NDIM + n0) * CDIM;
        #pragma unroll
        for (int i = 0; i < 16; ++i) {
            int f = tid + i * 256;      // 4096 c-pairs
            int j = f >> 6, c2 = f & 63;
            float r = rn[j];
            unsigned pk = pack2bf(T[c2 * 2][j] * r, T[c2 * 2 + 1][j] * r);
            *(unsigned*)((unsigned short*)kt + (size_t)j * CDIM + c2 * 2) = pk;
        }
        __hip_bfloat16* vb = (__hip_bfloat16*)((char*)ws + VB_OFF) + (size_t)b * CDIM * NDIM + n0;
        #pragma unroll
        for (int i = 0; i < 8; ++i) {
            int f = tid + i * 256;      // 2048 n-quads
            int c = f >> 4, j4 = f & 15;
            float4 v = *(const float4*)&T[c][j4 * 4];
            uint2 pv; pv.x = pack2bf(v.x, v.y); pv.y = pack2bf(v.z, v.w);
            *(uint2*)((unsigned short*)vb + (size_t)c * NDIM + j4 * 4) = pv;
        }
    } else {
        __hip_bfloat16* qt = (__hip_bfloat16*)((char*)ws + QT_OFF) + ((size_t)b * NDIM + n0) * CDIM;
        #pragma unroll
        for (int i = 0; i < 16; ++i) {
            int f = tid + i * 256;
            int j = f >> 6, c2 = f & 63;
            float r = rn[j];
            unsigned pk = pack2bf(T[c2 * 2][j] * r, T[c2 * 2 + 1][j] * r);
            *(unsigned*)((unsigned short*)qt + (size_t)j * CDIM + c2 * 2) = pk;
        }
    }
}

// ---------------------------------------------------------------------------
// Pass 1b: transpose weight to bf16 wT[o][c]; fold BN into scale/bias.
// ---------------------------------------------------------------------------
__global__ __launch_bounds__(256) void prep_w(const float* __restrict__ wgt,
                                              const float* __restrict__ gamma,
                                              const float* __restrict__ beta,
                                              const float* __restrict__ mean,
                                              const float* __restrict__ var,
                                              void* __restrict__ ws) {
    __hip_bfloat16* wT = (__hip_bfloat16*)((char*)ws + WT_OFF);
    float* sc = (float*)((char*)ws + SC_OFF);
    float* bi = (float*)((char*)ws + BI_OFF);
    const int tid = threadIdx.x;
    #pragma unroll
    for (int i = 0; i < 64; ++i) {
        int f = tid + i * 256;          // 16384
        int c = f >> 7, o = f & 127;
        wT[o * 128 + c] = __hip_bfloat16(wgt[c * 128 + o]);
    }
    if (tid < 128) {
        float inv = rsqrtf(var[tid] + 1e-5f);
        float s = inv * gamma[tid];
        sc[tid] = s;
        bi[tid] = beta[tid] - mean[tid] * s;
    }
}

// ---------------------------------------------------------------------------
// Pass 2: flash attention + projection + LeakyReLU + BN + transposed store.
// 512 threads = 8 waves. Waves 0-3 sweep n in [0,2048), waves 4-7 in
// [2048,4096) (in-block split-N; O/l combined through LDS at the end).
// Within a 4-wave half: wave wq owns m-slice wq*16 for S^T; PV is c-split
// (wave wq owns c-block wq*32), so each wave's O^T covers all 64 m.
// S^T = K*Q^T (A=K from LDS, B=Q regs) -> C-layout rows = n -> P packs into
// ds_write_b64 (n-contiguous). Static softmax max (cos-sim): P = exp(S-1);
// l accumulated as plain f32 per lane.
// K/V staged via global_load_lds width=16 into XOR-swizzled linear tiles.
// LDS map (dynamic, 81920 B): sK0@0, sV0@16K, sK1@32K, sV1@48K (16 KB each),
// sP0@64K, sP1@72K (8 KB each). Epilogue reuse: sO32 f32[128][66]@0,
// lLds f32[2][64]@34304, sAgg bf16[64][128]swz@36864, sRes f32[128][68]@0.
// ---------------------------------------------------------------------------
__global__ __launch_bounds__(512, 4) void flash2(const void* __restrict__ ws_,
                                                 float* __restrict__ out) {
    extern __shared__ char smem[];
    const char* ws = (const char*)ws_;
    const __hip_bfloat16* Qt = (const __hip_bfloat16*)(ws + QT_OFF);
    const __hip_bfloat16* Kt = (const __hip_bfloat16*)(ws + KT_OFF);
    const __hip_bfloat16* Vb = (const __hip_bfloat16*)(ws + VB_OFF);
    const __hip_bfloat16* wT = (const __hip_bfloat16*)(ws + WT_OFF);
    const float* scale = (const float*)(ws + SC_OFF);
    const float* bias  = (const float*)(ws + BI_OFF);

    const int b  = blockIdx.y;
    const int m0 = blockIdx.x * 64;
    const int tid = threadIdx.x;
    const int w = tid >> 6, lane = tid & 63;
    const int h = w >> 2, wq = w & 3;      // n-half, wave-in-half
    const int li = lane & 15, q = lane >> 4;

    char* sK = smem + h * 32768;           // 16 KB: [n 64][16B slot16 = cc ^ (n&15)]
    char* sV = smem + h * 32768 + 16384;   // 16 KB: [c 128][16B slot8 = nc ^ (c&7)]
    char* sP = smem + 65536 + h * 8192;    // 8 KB: [m 64][8B slot8 = c8 ^ ((m&7)<<1)]

    const __hip_bfloat16* kgb = Kt + (size_t)b * NDIM * CDIM;
    const __hip_bfloat16* vgb = Vb + (size_t)b * CDIM * NDIM;

    // Q B-fragments in registers: wave's m-slice = m0 + wq*16
    bf16x8 qf[4];
    {
        const __hip_bfloat16* qrow = Qt + ((size_t)b * NDIM + m0 + wq * 16 + li) * CDIM;
        #pragma unroll
        for (int ks = 0; ks < 4; ++ks)
            qf[ks] = *(const bf16x8*)(qrow + ks * 32 + q * 8);
    }

    // staging source pointers / LDS bases (global_load_lds: lane i -> base+i*16)
    const __hip_bfloat16* gK[4]; char* lK[4];
    const __hip_bfloat16* gV[4]; char* lV[4];
    #pragma unroll
    for (int i = 0; i < 4; ++i) {
        int s = (wq * 4 + i) * 64 + lane;
        int n = s >> 4, sl = s & 15;
        int cc = sl ^ (n & 15);
        gK[i] = kgb + (size_t)(h * 2048 + n) * CDIM + cc * 8;
        lK[i] = sK + (wq * 4 + i) * 1024;
        int s2 = s;
        int c = s2 >> 3, sl8 = s2 & 7;
        int nc = sl8 ^ (c & 7);
        gV[i] = vgb + (size_t)c * NDIM + h * 2048 + nc * 8;
        lV[i] = sV + (wq * 4 + i) * 1024;
    }

    const f32x4 z4 = {0.f, 0.f, 0.f, 0.f};
    f32x4 oaccT[2][4];                     // O^T[c-block ca][m-block mb], C-layout
    #pragma unroll
    for (int ca = 0; ca < 2; ++ca)
        #pragma unroll
        for (int mb = 0; mb < 4; ++mb) oaccT[ca][mb] = z4;
    float lacc = 0.f;

    for (int it = 0; it < 32; ++it) {
        __syncthreads();                   // prev iter's PV done: tiles + sP reusable
        #pragma unroll
        for (int i = 0; i < 4; ++i) { glds16(gK[i], lK[i]); gK[i] += 64 * CDIM; }
        #pragma unroll
        for (int i = 0; i < 4; ++i) { glds16(gV[i], lV[i]); gV[i] += 64; }
        __syncthreads();                   // tiles ready (vmcnt drained by barrier)

        // S^T = K . Q^T : D[n-row][m-col], rows = n (so P packs n-contiguous)
        f32x4 st[4];
        #pragma unroll
        for (int nb = 0; nb < 4; ++nb) st[nb] = z4;
        #pragma unroll
        for (int nb = 0; nb < 4; ++nb) {
            #pragma unroll
            for (int ks = 0; ks < 4; ++ks) {
                int n = nb * 16 + li;
                int sl = (ks * 4 + q) ^ li;          // cc ^ (n&15), n&15 == li
                bf16x8 kf = *(const bf16x8*)(sK + n * 256 + sl * 16);
                st[nb] = mfma16(kf, qf[ks], st[nb]);
            }
        }

        // P = exp(S-1), accumulate l, pack pairs, write b64 to shared sP
        #pragma unroll
        for (int nb = 0; nb < 4; ++nb) {
            float p0 = __expf(st[nb][0] - 1.0f);
            float p1 = __expf(st[nb][1] - 1.0f);
            float p2 = __expf(st[nb][2] - 1.0f);
            float p3 = __expf(st[nb][3] - 1.0f);
            lacc += (p0 + p1) + (p2 + p3);
            uint2 pk; pk.x = pack2bf(p0, p1); pk.y = pack2bf(p2, p3);
            int slot8 = (nb * 4 + q) ^ ((li & 7) << 1);
            *(uint2*)(sP + (wq * 16 + li) * 128 + slot8 * 8) = pk;
        }
        __syncthreads();                   // P ready for cross-wave PV

        // O^T += V . P^T : wave owns c-block wq*32 (ca 0..1), all 64 m
        #pragma unroll
        for (int ks2 = 0; ks2 < 2; ++ks2) {
            bf16x8 pf[4];
            #pragma unroll
            for (int mb = 0; mb < 4; ++mb) {
                int m = mb * 16 + li;
                int slot8 = ((ks2 * 4 + q) * 2) ^ ((li & 7) << 1);
                pf[mb] = *(const bf16x8*)(sP + m * 128 + slot8 * 8);
            }
            #pragma unroll
            for (int ca = 0; ca < 2; ++ca) {
                int c = (wq * 2 + ca) * 16 + li;
                int sl = (ks2 * 4 + q) ^ (li & 7);   // nc ^ (c&7), c&7 == li&7
                bf16x8 vf = *(const bf16x8*)(sV + c * 128 + sl * 16);
                #pragma unroll
                for (int mb = 0; mb < 4; ++mb)
                    oaccT[ca][mb] = mfma16(vf, pf[mb], oaccT[ca][mb]);
            }
        }
    }

    // ---- epilogue: combine halves, normalize, project, BN, store ----
    float lsum = lacc;
    lsum += __shfl_xor(lsum, 16, 64);
    lsum += __shfl_xor(lsum, 32, 64);      // full q-sum for m = wq*16+li (per half)

    __syncthreads();                                   // E1: main loop fully done
    float* lLds = (float*)(smem + 34304);              // [2][64]
    if (q == 0) lLds[h * 64 + wq * 16 + li] = lsum;
    float* sO32 = (float*)smem;                        // [128][66]
    if (h == 1) {
        #pragma unroll
        for (int ca = 0; ca < 2; ++ca)
            #pragma unroll
            for (int mb = 0; mb < 4; ++mb)
                #pragma unroll
                for (int r = 0; r < 4; ++r)
                    sO32[((wq * 2 + ca) * 16 + q * 4 + r) * 66 + mb * 16 + li] =
                        oaccT[ca][mb][r];
    }
    __syncthreads();                                   // E2
    __hip_bfloat16* sAgg = (__hip_bfloat16*)(smem + 36864);  // [64 m][128 c] swz
    if (h == 0) {
        float linv[4];
        #pragma unroll
        for (int mb = 0; mb < 4; ++mb)
            linv[mb] = 1.0f / (lLds[mb * 16 + li] + lLds[64 + mb * 16 + li]);
        #pragma unroll
        for (int ca = 0; ca < 2; ++ca) {
            #pragma unroll
            for (int mb = 0; mb < 4; ++mb) {
                float v0 = (oaccT[ca][mb][0] + sO32[((wq*2+ca)*16 + q*4 + 0) * 66 + mb*16 + li]) * linv[mb];
                float v1 = (oaccT[ca][mb][1] + sO32[((wq*2+ca)*16 + q*4 + 1) * 66 + mb*16 + li]) * linv[mb];
                float v2 = (oaccT[ca][mb][2] + sO32[((wq*2+ca)*16 + q*4 + 2) * 66 + mb*16 + li]) * linv[mb];
                float v3 = (oaccT[ca][mb][3] + sO32[((wq*2+ca)*16 + q*4 + 3) * 66 + mb*16 + li]) * linv[mb];
                uint2 pk; pk.x = pack2bf(v0, v1); pk.y = pack2bf(v2, v3);
                int m = mb * 16 + li;
                int c8 = (wq * 2 + ca) * 4 + q;        // (c-base)/4, c-base=(wq*2+ca)*16+q*4
                int slot8 = c8 ^ ((m & 7) << 1);
                *(uint2*)((char*)sAgg + m * 256 + slot8 * 8) = pk;
            }
        }
    }
    __syncthreads();                                   // E3: sAgg ready; sO32 dead

    // projection: all 8 waves; wave -> m-slice (w&3)*16, o-half (w>>2)*64
    const int mslice = (w & 3) * 16;
    const int ohalf = (w >> 2) * 64;
    f32x4 racc[4];
    #pragma unroll
    for (int ob = 0; ob < 4; ++ob) racc[ob] = z4;
    #pragma unroll
    for (int ks = 0; ks < 4; ++ks) {
        int slot8 = ((ks * 4 + q) * 2) ^ ((li & 7) << 1);
        bf16x8 af = *(const bf16x8*)((char*)sAgg + (mslice + li) * 256 + slot8 * 8);
        #pragma unroll
        for (int ob = 0; ob < 4; ++ob) {
            bf16x8 wf = *(const bf16x8*)(wT + (size_t)(ohalf + ob * 16 + li) * CDIM + ks * 32 + q * 8);
            racc[ob] = mfma16(af, wf, racc[ob]);
        }
    }

    // LeakyReLU + BN(eval) -> transpose buffer
    float* sRes = (float*)smem;                        // [128][68] (sO32 dead)
    #pragma unroll
    for (int ob = 0; ob < 4; ++ob) {
        int o = ohalf + ob * 16 + li;
        float sc = scale[o], bi = bias[o];
        #pragma unroll
        for (int r = 0; r < 4; ++r) {
            float v = racc[ob][r];
            v = (v >= 0.0f) ? v : 0.01f * v;
            v = v * sc + bi;
            sRes[o * 68 + mslice + q * 4 + r] = v;
        }
    }
    __syncthreads();                                   // E4

    // coalesced store: out[b][o][m0..m0+63]
    float* outb = out + (size_t)b * CDIM * NDIM + m0;
    #pragma unroll
    for (int i = 0; i < 4; ++i) {
        int f = tid + i * 512;          // 2048 float4s
        int o = f >> 4, mq = f & 15;
        *(float4*)(outb + (size_t)o * NDIM + mq * 4) = *(const float4*)(sRes + o * 68 + mq * 4);
    }
}

extern "C" void kernel_launch(void* const* d_in, const int* in_sizes, int n_in,
                              void* d_out, int out_size, void* d_ws, size_t ws_size,
                              hipStream_t stream) {
    const float* input  = (const float*)d_in[0];
    const float* tg     = (const float*)d_in[1];
    const float* weight = (const float*)d_in[2];
    const float* gamma  = (const float*)d_in[3];
    const float* beta   = (const float*)d_in[4];
    const float* rmean  = (const float*)d_in[5];
    const float* rvar   = (const float*)d_in[6];
    float* out = (float*)d_out;

    (void)in_sizes; (void)n_in; (void)out_size; (void)ws_size;

    // opt-in to 80 KB dynamic LDS (idempotent; host-side, capture-safe)
    hipFuncSetAttribute(reinterpret_cast<const void*>(flash2),
                        hipFuncAttributeMaxDynamicSharedMemorySize, 81920);

    dim3 gprep(NDIM / 64, BATCH, 2);
    prep_nt<<<gprep, 256, 0, stream>>>(input, tg, d_ws);
    prep_w<<<dim3(1), 256, 0, stream>>>(weight, gamma, beta, rmean, rvar, d_ws);
    dim3 gflash(NDIM / 64, BATCH);
    flash2<<<gflash, 512, 81920, stream>>>(d_ws, out);
}

// Round 3
// 199.466 us; speedup vs baseline: 1.2044x; 1.0112x over previous
//
#include <hip/hip_runtime.h>
#include <hip/hip_bf16.h>

// Problem constants (fixed by reference): B=8, C=128, N=M=4096, OUT=128
#define BATCH 8
#define CDIM 128
#define NDIM 4096

typedef __bf16 bf16x8 __attribute__((ext_vector_type(8)));
typedef float f32x4 __attribute__((ext_vector_type(4)));

// workspace layout (bytes)
#define QT_OFF 0u                      // bf16 [8][4096][128]  normalized target_g, transposed
#define KT_OFF 8388608u                // bf16 [8][4096][128]  normalized input, transposed
#define VB_OFF 16777216u               // bf16 [8][128][4096]  raw input
#define WT_OFF 25165824u               // bf16 [128][128]      weight transposed: wT[o][c]
#define SC_OFF (WT_OFF + 32768u)       // f32 [128] scale = gamma*rsqrt(var+eps)
#define BI_OFF (SC_OFF + 512u)         // f32 [128] bias  = beta - mean*scale

__device__ __forceinline__ f32x4 mfma16(bf16x8 a, bf16x8 b, f32x4 c) {
    return __builtin_amdgcn_mfma_f32_16x16x32_bf16(a, b, c, 0, 0, 0);
}

__device__ __forceinline__ unsigned pack2bf(float a, float b) {
    unsigned short ul = __builtin_bit_cast(unsigned short, (__bf16)a);
    unsigned short uh = __builtin_bit_cast(unsigned short, (__bf16)b);
    return (unsigned)ul | ((unsigned)uh << 16);
}

__device__ __forceinline__ void glds16(const void* g, void* l) {
    __builtin_amdgcn_global_load_lds((__attribute__((address_space(1))) void*)(void*)g,
                                     (__attribute__((address_space(3))) void*)l, 16, 0, 0);
}

// ---------------------------------------------------------------------------
// Pass 1a: per-column L2 normalize over C + transpose to [n][c] bf16.
// Transpose-at-write LDS layout Tt[n][c] pitch 129: all phases <=2-way banks.
// z==0: input -> Kt (normalized, [n][c]) + Vb (raw bf16, [c][n])
// z==1: target_g -> Qt
// ---------------------------------------------------------------------------
__global__ __launch_bounds__(256) void prep_nt(const float* __restrict__ input,
                                               const float* __restrict__ tg,
                                               void* __restrict__ ws) {
    __shared__ float Tt[64][129];     // [n-local][c], pitch 129 (odd word stride)
    __shared__ float psum[4][64];
    __shared__ float rn[64];
    const int n0 = blockIdx.x * 64;
    const int b  = blockIdx.y;
    const int tid = threadIdx.x;
    const float* src = (blockIdx.z == 0 ? input : tg) + (size_t)b * CDIM * NDIM;

    // load 128c x 64n tile (float4 along n), write transposed (4x b32, ~2-way)
    #pragma unroll
    for (int i = 0; i < 8; ++i) {
        int f = tid + i * 256;          // 2048 float4 slots
        int c = f >> 4, j4 = f & 15;
        float4 v = *(const float4*)(src + (size_t)c * NDIM + n0 + j4 * 4);
        Tt[j4 * 4 + 0][c] = v.x;
        Tt[j4 * 4 + 1][c] = v.y;
        Tt[j4 * 4 + 2][c] = v.z;
        Tt[j4 * 4 + 3][c] = v.w;
    }
    __syncthreads();
    {   // parallel sum-square over c (row-contiguous reads, conflict-free)
        int j = tid & 63, part = tid >> 6;
        float ss = 0.f;
        #pragma unroll 8
        for (int c = part * 32; c < part * 32 + 32; ++c) { float x = Tt[j][c]; ss += x * x; }
        psum[part][j] = ss;
    }
    __syncthreads();
    if (tid < 64) {
        float s = psum[0][tid] + psum[1][tid] + psum[2][tid] + psum[3][tid];
        rn[tid] = 1.0f / fmaxf(sqrtf(s), 1e-12f);
    }
    __syncthreads();

    __hip_bfloat16* dstT = (__hip_bfloat16*)((char*)ws + (blockIdx.z == 0 ? KT_OFF : QT_OFF))
                           + ((size_t)b * NDIM + n0) * CDIM;
    // normalized transposed store: lane handles 4 c of one row j -> 8B store
    #pragma unroll
    for (int i = 0; i < 8; ++i) {
        int f = tid + i * 256;          // 2048 c-quads
        int j = f >> 5, c4 = f & 31;
        float r = rn[j];
        float4 v = *(const float4*)&Tt[j][c4 * 4];   // b128, uniform 8-bank tiling
        uint2 pk; pk.x = pack2bf(v.x * r, v.y * r); pk.y = pack2bf(v.z * r, v.w * r);
        *(uint2*)((unsigned short*)dstT + (size_t)j * CDIM + c4 * 4) = pk;
    }
    if (blockIdx.z == 0) {
        __hip_bfloat16* vb = (__hip_bfloat16*)((char*)ws + VB_OFF) + (size_t)b * CDIM * NDIM + n0;
        #pragma unroll
        for (int i = 0; i < 8; ++i) {
            int f = tid + i * 256;      // 2048 n-quads
            int c = f >> 4, j4 = f & 15;
            float x0 = Tt[j4 * 4 + 0][c], x1 = Tt[j4 * 4 + 1][c];
            float x2 = Tt[j4 * 4 + 2][c], x3 = Tt[j4 * 4 + 3][c];
            uint2 pv; pv.x = pack2bf(x0, x1); pv.y = pack2bf(x2, x3);
            *(uint2*)((unsigned short*)vb + (size_t)c * NDIM + j4 * 4) = pv;
        }
    }
}

// ---------------------------------------------------------------------------
// Pass 1b: transpose weight to bf16 wT[o][c]; fold BN into scale/bias.
// ---------------------------------------------------------------------------
__global__ __launch_bounds__(256) void prep_w(const float* __restrict__ wgt,
                                              const float* __restrict__ gamma,
                                              const float* __restrict__ beta,
                                              const float* __restrict__ mean,
                                              const float* __restrict__ var,
                                              void* __restrict__ ws) {
    __hip_bfloat16* wT = (__hip_bfloat16*)((char*)ws + WT_OFF);
    float* sc = (float*)((char*)ws + SC_OFF);
    float* bi = (float*)((char*)ws + BI_OFF);
    const int tid = threadIdx.x;
    #pragma unroll
    for (int i = 0; i < 64; ++i) {
        int f = tid + i * 256;          // 16384
        int c = f >> 7, o = f & 127;
        wT[o * 128 + c] = __hip_bfloat16(wgt[c * 128 + o]);
    }
    if (tid < 128) {
        float inv = rsqrtf(var[tid] + 1e-5f);
        float s = inv * gamma[tid];
        sc[tid] = s;
        bi[tid] = beta[tid] - mean[tid] * s;
    }
}

// ---------------------------------------------------------------------------
// Pass 2 (flash3): 512 threads = 8 waves, halves h in {0,1} sweep disjoint
// 2048-n ranges. Within a half (4 waves, 64-n tile per iter):
//   S^T phase: wave (ns,ms) computes 32n x 32m; each kf LDS read reused
//   for 2 Q-frags (reads 16 -> 8 vs R2).
//   PV phase: wave (cs,ms) owns 64c x 32m, k = 64n (vf 8 + pf 4 reads).
// All loop-invariant LDS offsets hoisted into pre-loop register arrays.
// P = exp(S-1) (cos-sim static max); l as plain f32 lanes, 4 partials/m.
// LDS: sK0@0,sV0@16K,sK1@32K,sV1@48K, sP0@64K, sP1@72K (80 KB).
// Epilogue reuse: sO32 f32[128][66]@0, lLds f32[4][64]@34304,
// sAgg bf16[64][128]swz@36864, sRes f32[128][68]@0.
// ---------------------------------------------------------------------------
__global__ __launch_bounds__(512, 4) void flash3(const void* __restrict__ ws_,
                                                 float* __restrict__ out) {
    extern __shared__ char smem[];
    const char* ws = (const char*)ws_;
    const __hip_bfloat16* Qt = (const __hip_bfloat16*)(ws + QT_OFF);
    const __hip_bfloat16* Kt = (const __hip_bfloat16*)(ws + KT_OFF);
    const __hip_bfloat16* Vb = (const __hip_bfloat16*)(ws + VB_OFF);
    const __hip_bfloat16* wT = (const __hip_bfloat16*)(ws + WT_OFF);
    const float* scale = (const float*)(ws + SC_OFF);
    const float* bias  = (const float*)(ws + BI_OFF);

    const int b  = blockIdx.y;
    const int m0 = blockIdx.x * 64;
    const int tid = threadIdx.x;
    const int w = tid >> 6, lane = tid & 63;
    const int h = w >> 2, wq = w & 3;
    const int li = lane & 15, q = lane >> 4;
    const int ns = wq >> 1, ms = wq & 1;   // S-phase split
    const int cs = wq >> 1;                // PV c-half (same bit as ns)

    const __hip_bfloat16* kgb = Kt + (size_t)b * NDIM * CDIM;
    const __hip_bfloat16* vgb = Vb + (size_t)b * CDIM * NDIM;

    // Q B-fragments in registers: rows m0 + ms*32 + mb*16 + li
    bf16x8 qf[2][4];
    #pragma unroll
    for (int mb = 0; mb < 2; ++mb) {
        const __hip_bfloat16* qrow = Qt + ((size_t)b * NDIM + m0 + ms * 32 + mb * 16 + li) * CDIM;
        #pragma unroll
        for (int ks = 0; ks < 4; ++ks)
            qf[mb][ks] = *(const bf16x8*)(qrow + ks * 32 + q * 8);
    }

    // hoisted loop-invariant LDS byte offsets
    unsigned kOff[2][4];                   // S^T kf reads
    #pragma unroll
    for (int nb = 0; nb < 2; ++nb)
        #pragma unroll
        for (int ks = 0; ks < 4; ++ks) {
            int n = ns * 32 + nb * 16 + li;
            kOff[nb][ks] = h * 32768 + n * 256 + (((ks * 4 + q) ^ li)) * 16;
        }
    unsigned vOff[2][4];                   // PV vf reads
    #pragma unroll
    for (int k2 = 0; k2 < 2; ++k2)
        #pragma unroll
        for (int ca = 0; ca < 4; ++ca) {
            int c = cs * 64 + ca * 16 + li;
            vOff[k2][ca] = h * 32768 + 16384 + c * 128 + (((k2 * 4 + q) ^ (li & 7))) * 16;
        }
    unsigned pOff[2][2];                   // PV pf reads
    #pragma unroll
    for (int k2 = 0; k2 < 2; ++k2)
        #pragma unroll
        for (int mb = 0; mb < 2; ++mb)
            pOff[k2][mb] = 65536 + h * 8192 + (ms * 32 + mb * 16 + li) * 128
                           + (((k2 * 8 + q * 2) ^ ((li & 7) << 1))) * 8;
    unsigned wOff[2][2];                   // P writes
    #pragma unroll
    for (int nb = 0; nb < 2; ++nb)
        #pragma unroll
        for (int mb = 0; mb < 2; ++mb)
            wOff[nb][mb] = 65536 + h * 8192 + (ms * 32 + mb * 16 + li) * 128
                           + (((ns * 8 + nb * 4 + q) ^ ((li & 7) << 1))) * 8;

    // staging: global sources + LDS dest offsets (glds: lane -> base + lane*16)
    const __hip_bfloat16* gK[4]; const __hip_bfloat16* gV[4];
    unsigned lKo[4], lVo[4];
    #pragma unroll
    for (int i = 0; i < 4; ++i) {
        int s = (wq * 4 + i) * 64 + lane;
        int n = s >> 4, sl = s & 15;
        int cc = sl ^ (n & 15);
        gK[i] = kgb + (size_t)(h * 2048 + n) * CDIM + cc * 8;
        lKo[i] = h * 32768 + (wq * 4 + i) * 1024;
        int c = s >> 3, sl8 = s & 7;
        int nc = sl8 ^ (c & 7);
        gV[i] = vgb + (size_t)c * NDIM + h * 2048 + nc * 8;
        lVo[i] = h * 32768 + 16384 + (wq * 4 + i) * 1024;
    }

    const f32x4 z4 = {0.f, 0.f, 0.f, 0.f};
    f32x4 oacc[4][2];
    #pragma unroll
    for (int ca = 0; ca < 4; ++ca) { oacc[ca][0] = z4; oacc[ca][1] = z4; }
    float lac0 = 0.f, lac1 = 0.f;

    for (int it = 0; it < 32; ++it) {
        __syncthreads();                   // prev PV done: tiles + sP reusable
        #pragma unroll
        for (int i = 0; i < 4; ++i) { glds16(gK[i], smem + lKo[i]); gK[i] += 64 * CDIM; }
        #pragma unroll
        for (int i = 0; i < 4; ++i) { glds16(gV[i], smem + lVo[i]); gV[i] += 64; }
        __syncthreads();                   // tiles ready

        // S^T = K.Q^T, nb sequential (st regs small, exp overlaps next MFMA)
        #pragma unroll
        for (int nb = 0; nb < 2; ++nb) {
            f32x4 st0 = z4, st1 = z4;
            #pragma unroll
            for (int ks = 0; ks < 4; ++ks) {
                bf16x8 kf = *(const bf16x8*)(smem + kOff[nb][ks]);
                st0 = mfma16(kf, qf[0][ks], st0);
                st1 = mfma16(kf, qf[1][ks], st1);
            }
            {
                float p0 = __expf(st0[0] - 1.0f), p1 = __expf(st0[1] - 1.0f);
                float p2 = __expf(st0[2] - 1.0f), p3 = __expf(st0[3] - 1.0f);
                lac0 += (p0 + p1) + (p2 + p3);
                uint2 pk; pk.x = pack2bf(p0, p1); pk.y = pack2bf(p2, p3);
                *(uint2*)(smem + wOff[nb][0]) = pk;
            }
            {
                float p0 = __expf(st1[0] - 1.0f), p1 = __expf(st1[1] - 1.0f);
                float p2 = __expf(st1[2] - 1.0f), p3 = __expf(st1[3] - 1.0f);
                lac1 += (p0 + p1) + (p2 + p3);
                uint2 pk; pk.x = pack2bf(p0, p1); pk.y = pack2bf(p2, p3);
                *(uint2*)(smem + wOff[nb][1]) = pk;
            }
        }
        __syncthreads();                   // P ready for cross-wave PV

        // O^T += V.P^T : wave owns 64c x 32m over k=64n
        #pragma unroll
        for (int k2 = 0; k2 < 2; ++k2) {
            bf16x8 pf0 = *(const bf16x8*)(smem + pOff[k2][0]);
            bf16x8 pf1 = *(const bf16x8*)(smem + pOff[k2][1]);
            #pragma unroll
            for (int ca = 0; ca < 4; ++ca) {
                bf16x8 vf = *(const bf16x8*)(smem + vOff[k2][ca]);
                oacc[ca][0] = mfma16(vf, pf0, oacc[ca][0]);
                oacc[ca][1] = mfma16(vf, pf1, oacc[ca][1]);
            }
        }
    }

    // ---- epilogue ----
    lac0 += __shfl_xor(lac0, 16, 64); lac0 += __shfl_xor(lac0, 32, 64);
    lac1 += __shfl_xor(lac1, 16, 64); lac1 += __shfl_xor(lac1, 32, 64);

    __syncthreads();                                   // E1: main loop fully done
    float* lLds = (float*)(smem + 34304);              // [4][64] partials
    if (q == 0) {
        lLds[(h * 2 + ns) * 64 + ms * 32 + li] = lac0;
        lLds[(h * 2 + ns) * 64 + ms * 32 + 16 + li] = lac1;
    }
    float* sO32 = (float*)smem;                        // [128][66]
    if (h == 1) {
        #pragma unroll
        for (int ca = 0; ca < 4; ++ca)
            #pragma unroll
            for (int mb = 0; mb < 2; ++mb)
                #pragma unroll
                for (int r = 0; r < 4; ++r)
                    sO32[(cs * 64 + ca * 16 + q * 4 + r) * 66 + ms * 32 + mb * 16 + li] =
                        oacc[ca][mb][r];
    }
    __syncthreads();                                   // E2
    __hip_bfloat16* sAgg = (__hip_bfloat16*)(smem + 36864);  // [64 m][128 c] swz
    if (h == 0) {
        float linv[2]; int mm[2];
        #pragma unroll
        for (int mb = 0; mb < 2; ++mb) {
            int m = ms * 32 + mb * 16 + li;
            mm[mb] = m;
            linv[mb] = 1.0f / (lLds[m] + lLds[64 + m] + lLds[128 + m] + lLds[192 + m]);
        }
        #pragma unroll
        for (int ca = 0; ca < 4; ++ca) {
            #pragma unroll
            for (int mb = 0; mb < 2; ++mb) {
                int m = mm[mb];
                float v0 = (oacc[ca][mb][0] + sO32[(cs*64 + ca*16 + q*4 + 0) * 66 + m]) * linv[mb];
                float v1 = (oacc[ca][mb][1] + sO32[(cs*64 + ca*16 + q*4 + 1) * 66 + m]) * linv[mb];
                float v2 = (oacc[ca][mb][2] + sO32[(cs*64 + ca*16 + q*4 + 2) * 66 + m]) * linv[mb];
                float v3 = (oacc[ca][mb][3] + sO32[(cs*64 + ca*16 + q*4 + 3) * 66 + m]) * linv[mb];
                uint2 pk; pk.x = pack2bf(v0, v1); pk.y = pack2bf(v2, v3);
                int c8 = cs * 16 + ca * 4 + q;         // c-quad index 0..31
                int slot8 = c8 ^ ((li & 7) << 1);
                *(uint2*)((char*)sAgg + m * 256 + slot8 * 8) = pk;
            }
        }
    }
    __syncthreads();                                   // E3: sAgg ready

    // projection: all 8 waves; wave -> m-slice (w&3)*16, o-half (w>>2)*64
    const int mslice = (w & 3) * 16;
    const int ohalf = (w >> 2) * 64;
    f32x4 racc[4];
    #pragma unroll
    for (int ob = 0; ob < 4; ++ob) racc[ob] = z4;
    #pragma unroll
    for (int ks = 0; ks < 4; ++ks) {
        int slot8 = ((ks * 4 + q) * 2) ^ ((li & 7) << 1);
        bf16x8 af = *(const bf16x8*)((char*)sAgg + (mslice + li) * 256 + slot8 * 8);
        #pragma unroll
        for (int ob = 0; ob < 4; ++ob) {
            bf16x8 wf = *(const bf16x8*)(wT + (size_t)(ohalf + ob * 16 + li) * CDIM + ks * 32 + q * 8);
            racc[ob] = mfma16(af, wf, racc[ob]);
        }
    }

    // LeakyReLU + BN(eval) -> transpose buffer
    float* sRes = (float*)smem;                        // [128][68]
    #pragma unroll
    for (int ob = 0; ob < 4; ++ob) {
        int o = ohalf + ob * 16 + li;
        float sc = scale[o], bi = bias[o];
        #pragma unroll
        for (int r = 0; r < 4; ++r) {
            float v = racc[ob][r];
            v = (v >= 0.0f) ? v : 0.01f * v;
            v = v * sc + bi;
            sRes[o * 68 + mslice + q * 4 + r] = v;
        }
    }
    __syncthreads();                                   // E4

    // coalesced store: out[b][o][m0..m0+63]
    float* outb = out + (size_t)b * CDIM * NDIM + m0;
    #pragma unroll
    for (int i = 0; i < 4; ++i) {
        int f = tid + i * 512;          // 2048 float4s
        int o = f >> 4, mq = f & 15;
        *(float4*)(outb + (size_t)o * NDIM + mq * 4) = *(const float4*)(sRes + o * 68 + mq * 4);
    }
}

extern "C" void kernel_launch(void* const* d_in, const int* in_sizes, int n_in,
                              void* d_out, int out_size, void* d_ws, size_t ws_size,
                              hipStream_t stream) {
    const float* input  = (const float*)d_in[0];
    const float* tg     = (const float*)d_in[1];
    const float* weight = (const float*)d_in[2];
    const float* gamma  = (const float*)d_in[3];
    const float* beta   = (const float*)d_in[4];
    const float* rmean  = (const float*)d_in[5];
    const float* rvar   = (const float*)d_in[6];
    float* out = (float*)d_out;

    (void)in_sizes; (void)n_in; (void)out_size; (void)ws_size;

    hipFuncSetAttribute(reinterpret_cast<const void*>(flash3),
                        hipFuncAttributeMaxDynamicSharedMemorySize, 81920);

    dim3 gprep(NDIM / 64, BATCH, 2);
    prep_nt<<<gprep, 256, 0, stream>>>(input, tg, d_ws);
    prep_w<<<dim3(1), 256, 0, stream>>>(weight, gamma, beta, rmean, rvar, d_ws);
    dim3 gflash(NDIM / 64, BATCH);
    flash3<<<gflash, 512, 81920, stream>>>(d_ws, out);
}